// Round 19
// baseline (209.293 us; speedup 1.0000x reference)
//
#include <hip/hip_runtime.h>
#include <math.h>

#define NBINS   64
#define GROUPS  16
#define HIDDEN  128
#define EPSF    1e-6f

// B=2, C=16, H=W=1024; 32 images of 1M floats; 32x32 tiles of 32x32 elems.
#define IMG_ELEMS   (1024*1024)
#define F4_PER_ROW  256          // 1024 cols / 4
#define NIMG        32           // B*C

typedef float nfloat4 __attribute__((ext_vector_type(4)));  // builtin-compatible

// Agent-scope relaxed atomic load/store: compile to plain coalescing
// global_load/store with cache-bypass bits (coherent at L3). NOT RMWs
// (R13's 160us tail) and no __threadfence L2-invalidate storms (R12).
__device__ __forceinline__ float  ald(const float* p)
{ return __hip_atomic_load(p, __ATOMIC_RELAXED, __HIP_MEMORY_SCOPE_AGENT); }
__device__ __forceinline__ void   ast(float* p, float v)
{ __hip_atomic_store(p, v, __ATOMIC_RELAXED, __HIP_MEMORY_SCOPE_AGENT); }
__device__ __forceinline__ unsigned arrive(unsigned* p)
{ return __hip_atomic_fetch_add(p, 1u, __ATOMIC_RELEASE, __HIP_MEMORY_SCOPE_AGENT); }

// counters zeroed each replay (poison-safe)
__global__ void k_zero(unsigned* cnt)
{
    for (int o = threadIdx.x; o < 1056; o += 256) cnt[o] = 0u;
}

// ---------------------------------------------------------------------------
// Kernel A (1024 blocks x 256): P1 stats; per-image last-arriver runs P2
// (minmax finalize + ballot hist -> pcdf); last worker runs P3 (conv1 +
// shuffle-conv2, all 128 ch, LDS-staged weights). All cross-block data moves
// via agent atomic load/store; arrives are release fetch_adds; winners' reads
// bypass L2 so no acquire/invalidate is needed anywhere.
// ---------------------------------------------------------------------------
__global__ __launch_bounds__(256) void k_A(
        const float* __restrict__ x,
        const float* __restrict__ w1, const float* __restrict__ b1,
        const float* __restrict__ w2, const float* __restrict__ b2,
        float* __restrict__ blocksum,   // [NIMG][1024]
        float* __restrict__ pmin,       // [NIMG*32]
        float* __restrict__ pmax,       // [NIMG*32]
        float* __restrict__ gmin, float* __restrict__ gmax,   // [NIMG]
        float* __restrict__ pcdf,       // [2][16][64]
        float* __restrict__ h2,         // [128][64]
        unsigned* __restrict__ cnt)     // [img*32] arrive; [1024] workers
{
    const int bid  = blockIdx.x;
    const int t    = threadIdx.x;
    const int lane = t & 63;
    const int wave = t >> 6;
    const int img  = bid >> 5;
    const int part = bid & 31;

    __shared__ float wmn[4], wmx[4];
    __shared__ unsigned s_old1, s_old2;
    __shared__ float s_mn, s_inv;
    __shared__ int   whist[4][NBINS];
    __shared__ float dcdf[GROUPS][NBINS];
    __shared__ float wchunk[32 * 80];     // 10KB w1 chunk (32 channels)
    __shared__ float w2s[32][5];
    __shared__ float b1s[32], b2s[32];

    // ================= Phase 1: per-chunk stats (all 1024 blocks) ==========
    {
        const float4* xin = (const float4*)(x + (size_t)img * IMG_ELEMS);
        const int rowbase = (part * 32) * F4_PER_ROW;

        float s = 0.f, mn = INFINITY, mx = -INFINITY;
        #pragma unroll 4
        for (int r = 0; r < 32; ++r) {
            float4 v = xin[rowbase + r * F4_PER_ROW + t];
            s += (v.x + v.y) + (v.z + v.w);
            mn = fminf(mn, fminf(fminf(v.x, v.y), fminf(v.z, v.w)));
            mx = fmaxf(mx, fmaxf(fmaxf(v.x, v.y), fmaxf(v.z, v.w)));
        }
        s += __shfl_xor(s, 4, 64);
        s += __shfl_xor(s, 2, 64);
        s += __shfl_xor(s, 1, 64);
        if ((t & 7) == 0)
            ast(&blocksum[img * 1024 + part * 32 + (t >> 3)], s);

        #pragma unroll
        for (int st = 32; st > 0; st >>= 1) {
            mn = fminf(mn, __shfl_xor(mn, st, 64));
            mx = fmaxf(mx, __shfl_xor(mx, st, 64));
        }
        if (lane == 0) { wmn[wave] = mn; wmx[wave] = mx; }
        __syncthreads();
        if (t == 0) {
            ast(&pmin[bid], fminf(fminf(wmn[0], wmn[1]), fminf(wmn[2], wmn[3])));
            ast(&pmax[bid], fmaxf(fmaxf(wmx[0], wmx[1]), fmaxf(wmx[2], wmx[3])));
        }
    }

    // arrive (release: publishes ordered before the add); last = worker
    __syncthreads();
    if (t == 0) s_old1 = arrive(&cnt[img * 32]);
    __syncthreads();
    if (s_old1 != 31u) return;       // 992 blocks exit here

    // ================= Phase 2: minmax finalize + ballot histogram =========
    {
        const int bc = img;
        if (wave == 0) {
            float mn = (lane < 32) ? ald(&pmin[bc * 32 + lane]) : INFINITY;
            float mx = (lane < 32) ? ald(&pmax[bc * 32 + lane]) : -INFINITY;
            #pragma unroll
            for (int st = 32; st > 0; st >>= 1) {
                mn = fminf(mn, __shfl_xor(mn, st, 64));
                mx = fmaxf(mx, __shfl_xor(mx, st, 64));
            }
            if (lane == 0) {
                gmin[bc] = mn; gmax[bc] = mx;   // plain: consumed by k_B only
                s_mn = mn; s_inv = 1.0f / (mx - mn + EPSF);
            }
        }
        __syncthreads();
        const float mnv = s_mn;
        const float inv = s_inv;

        int idx0, idx1, idx2, idx3;
        {
            const float* bs = blocksum + bc * 1024;
            #define MKIDX(D, IT) { \
                float bmean = ald(&bs[t + (IT)*256]) * (1.0f / 1024.0f); \
                float xs = (bmean - mnv) * inv; \
                int id = (int)rintf(xs * 63.0f); \
                D = max(0, min(id, 63)); }
            MKIDX(idx0, 0) MKIDX(idx1, 1) MKIDX(idx2, 2) MKIDX(idx3, 3)
            #undef MKIDX
        }
        int cntv = 0;
        #pragma unroll 1
        for (int b = 0; b < NBINS; ++b) {
            int p = __popcll(__ballot(idx0 == b)) + __popcll(__ballot(idx1 == b))
                  + __popcll(__ballot(idx2 == b)) + __popcll(__ballot(idx3 == b));
            cntv += (lane == b) ? p : 0;
        }
        whist[wave][lane] = cntv;
        __syncthreads();
        if (t < NBINS) {
            int h = whist[0][t] + whist[1][t] + whist[2][t] + whist[3][t];
            #pragma unroll
            for (int d = 1; d < 64; d <<= 1) {
                int v = __shfl_up(h, d, 64);
                if (t >= d) h += v;
            }
            ast(&pcdf[bc * NBINS + t], (float)h * (0.5f / (1024.0f + EPSF)));
        }
    }

    // workers arrive (release); last worker becomes the conv super-worker
    __syncthreads();
    if (t == 0) s_old2 = arrive(&cnt[1024]);
    __syncthreads();
    if (s_old2 != 31u) return;       // 31 workers exit here

    // ================= Phase 3: conv1 + shuffle conv2, ALL 128 channels ====
    {
        const int k = lane;
        // dcdf = sum of the two pre-scaled b-halves (bypass-L2 loads)
        for (int o = t; o < GROUPS * NBINS; o += 256)
            ((float*)dcdf)[o] = ald(&pcdf[o]) + ald(&pcdf[GROUPS * NBINS + o]);

        for (int cc = 0; cc < 4; ++cc) {
            __syncthreads();   // protect wchunk reuse
            for (int o = t; o < 32 * 80; o += 256) {
                const int ocl = o / 80, rem = o % 80;
                const int ic = rem / 5, tap = rem % 5;
                wchunk[o] = w1[((cc * 32 + ocl) * GROUPS + ic) * 25 + 10 + tap];
            }
            for (int o = t; o < 160; o += 256)
                w2s[o / 5][o % 5] = w2[(cc * 32 + o / 5) * 25 + 10 + o % 5];
            if (t < 32)       b1s[t] = b1[cc * 32 + t];
            else if (t < 64)  b2s[t - 32] = b2[cc * 32 + t - 32];
            __syncthreads();

            for (int r = 0; r < 8; ++r) {
                const int ocl = wave * 8 + r;
                const int oc  = cc * 32 + ocl;
                float acc = b1s[ocl];
                const float* wp = wchunk + ocl * 80;
                for (int ic = 0; ic < GROUPS; ++ic) {
                    #pragma unroll
                    for (int tap = 0; tap < 5; ++tap) {
                        const int kk = k - 2 + tap;
                        if (kk >= 0 && kk < NBINS)
                            acc += wp[ic * 5 + tap] * dcdf[ic][kk];
                    }
                }
                const float c1 = fmaxf(acc, 0.f);
                const float m2 = __shfl_up(c1, 2, 64);
                const float m1 = __shfl_up(c1, 1, 64);
                const float p1 = __shfl_down(c1, 1, 64);
                const float p2 = __shfl_down(c1, 2, 64);
                float a = b2s[ocl];
                a += w2s[ocl][0] * ((k >= 2) ? m2 : 0.f);
                a += w2s[ocl][1] * ((k >= 1) ? m1 : 0.f);
                a += w2s[ocl][2] * c1;
                a += w2s[ocl][3] * ((k <= 62) ? p1 : 0.f);
                a += w2s[ocl][4] * ((k <= 61) ? p2 : 0.f);
                h2[oc * NBINS + k] = fmaxf(a, 0.f);   // plain: k_B consumes
            }
        }
    }
}

// ---------------------------------------------------------------------------
// Kernel B: fused lut-finalize + elementwise remap (R9-proven, unchanged).
// ---------------------------------------------------------------------------
__global__ __launch_bounds__(256) void k_B(
        const float* __restrict__ x,
        const float* __restrict__ gmin, const float* __restrict__ gmax,
        const float* __restrict__ h2,
        const float* __restrict__ w3, const float* __restrict__ b3,
        const float* __restrict__ alpha,
        float* __restrict__ out)
{
    const int img  = blockIdx.x >> 6;
    const int part = blockIdx.x & 63;
    const int c    = img & 15;         // channel == group (C/G == 1)
    const int t    = threadIdx.x;
    const int q    = t >> 6;
    const int k    = t & 63;

    __shared__ float partial[4][NBINS];
    __shared__ float lut_s[NBINS];

    {
        float pa = 0.f;
        const float* w3p = w3 + c * HIDDEN + q * 32;
        const float* h2p = h2 + (q * 32) * NBINS + k;
        #pragma unroll 8
        for (int h = 0; h < 32; ++h)
            pa += w3p[h] * h2p[h * NBINS];
        partial[q][k] = pa;
    }
    __syncthreads();
    if (q == 0) {
        float acc = b3[c] + ((partial[0][k] + partial[1][k])
                           + (partial[2][k] + partial[3][k]));
        float d = fmaxf(acc, 0.f) + log1pf(expf(-fabsf(acc)));  // softplus
        #pragma unroll
        for (int dd = 1; dd < 64; dd <<= 1) {
            float v = __shfl_up(d, dd, 64);
            if (k >= dd) d += v;
        }
        const float tot = __shfl(d, 63, 64);
        lut_s[k] = d / (tot + EPSF) + (float)k * (1.0f / 63.0f);
    }
    __syncthreads();

    const float mnv = gmin[img];
    const float mxv = gmax[img];
    const float r   = mxv - mnv;
    const float inv = 1.0f / (r + EPSF);
    const float aa  = 1.0f / (1.0f + expf(-alpha[0]));

    const size_t base4 = (size_t)img * (IMG_ELEMS / 4) + (size_t)part * 4096;
    const float4* xin = (const float4*)x;
    nfloat4* o4 = (nfloat4*)out;

    #pragma unroll 2
    for (int it = 0; it < 16; ++it) {
        const size_t f = base4 + (size_t)t + (size_t)it * 256;
        float4 v = xin[f];
        nfloat4 w;
        #define REMAP(DST, SRC) { \
            float x01 = (SRC - mnv) * inv; \
            float pos = x01 * 63.0f; \
            int il = max(0, min((int)floorf(pos), 63)); \
            int ih = min(il + 1, 63); \
            float wt = pos - (float)il; \
            float vlo = lut_s[il], vhi = lut_s[ih]; \
            DST = (aa * fmaf(wt, vhi - vlo, vlo) + (1.0f - aa) * x01) * r + mnv; }
        REMAP(w.x, v.x) REMAP(w.y, v.y) REMAP(w.z, v.z) REMAP(w.w, v.w)
        #undef REMAP
        __builtin_nontemporal_store(w, &o4[f]);
    }
}

// ---------------------------------------------------------------------------
extern "C" void kernel_launch(void* const* d_in, const int* in_sizes, int n_in,
                              void* d_out, int out_size, void* d_ws, size_t ws_size,
                              hipStream_t stream)
{
    const float* x     = (const float*)d_in[0];
    const float* w1    = (const float*)d_in[1];
    const float* b1    = (const float*)d_in[2];
    const float* w2    = (const float*)d_in[3];
    const float* b2    = (const float*)d_in[4];
    const float* w3    = (const float*)d_in[5];
    const float* b3    = (const float*)d_in[6];
    const float* alpha = (const float*)d_in[7];
    float* out = (float*)d_out;

    float* ws = (float*)d_ws;
    float* blocksum = ws;            // 32768
    float* pmin     = ws + 32768;    // 1024
    float* pmax     = ws + 33792;    // 1024
    float* gmin     = ws + 34816;    // 32
    float* gmax     = ws + 34848;    // 32
    float* pcdf     = ws + 34880;    // 2048
    float* h2       = ws + 36928;    // 8192
    unsigned* cnt   = (unsigned*)(ws + 45120);  // 1056 uints

    k_zero<<<1,         256, 0, stream>>>(cnt);
    k_A   <<<NIMG * 32, 256, 0, stream>>>(x, w1, b1, w2, b2,
                                          blocksum, pmin, pmax,
                                          gmin, gmax, pcdf, h2, cnt);
    k_B   <<<NIMG * 64, 256, 0, stream>>>(x, gmin, gmax, h2, w3, b3, alpha, out);
}

// Round 20
// 82.087 us; speedup vs baseline: 2.5497x; 2.5497x over previous
//
#include <hip/hip_runtime.h>
#include <math.h>

#define NBINS   64
#define GROUPS  16
#define HIDDEN  128
#define EPSF    1e-6f

// B=2, C=16, H=W=1024; 32 images of 1M floats; 32x32 tiles of 32x32 elems.
#define IMG_ELEMS   (1024*1024)
#define F4_PER_ROW  256          // 1024 cols / 4
#define NIMG        32           // B*C

typedef float nfloat4 __attribute__((ext_vector_type(4)));  // builtin-compatible

// ---------------------------------------------------------------------------
// Kernel 1: per image-row-chunk (32 rows): min/max partials + 32 tile sums.
// grid = NIMG*32 blocks, 256 threads.
// ---------------------------------------------------------------------------
__global__ __launch_bounds__(256) void k_stats(
        const float* __restrict__ x,
        float* __restrict__ blocksum,   // [NIMG][1024] tile sums
        float* __restrict__ pmin,       // [NIMG*32]
        float* __restrict__ pmax)       // [NIMG*32]
{
    const int bid = blockIdx.x;
    const int bc  = bid >> 5;   // image
    const int i   = bid & 31;   // tile row
    const int t   = threadIdx.x;
    const int lane = t & 63;
    const int wave = t >> 6;

    const float4* xin = (const float4*)(x + (size_t)bc * IMG_ELEMS);
    const int rowbase = (i * 32) * F4_PER_ROW;

    float s = 0.f, mn = INFINITY, mx = -INFINITY;
    #pragma unroll 4
    for (int r = 0; r < 32; ++r) {
        float4 v = xin[rowbase + r * F4_PER_ROW + t];
        s += (v.x + v.y) + (v.z + v.w);
        mn = fminf(mn, fminf(fminf(v.x, v.y), fminf(v.z, v.w)));
        mx = fmaxf(mx, fmaxf(fmaxf(v.x, v.y), fmaxf(v.z, v.w)));
    }

    // tile sums: 8 consecutive threads share tile j = t>>3 (within a wave)
    s += __shfl_xor(s, 4, 64);
    s += __shfl_xor(s, 2, 64);
    s += __shfl_xor(s, 1, 64);
    if ((t & 7) == 0)
        blocksum[bc * 1024 + i * 32 + (t >> 3)] = s;

    // block-wide min/max: wave shuffle reduce, then cross-wave via LDS
    #pragma unroll
    for (int st = 32; st > 0; st >>= 1) {
        mn = fminf(mn, __shfl_xor(mn, st, 64));
        mx = fmaxf(mx, __shfl_xor(mx, st, 64));
    }
    __shared__ float wmn[4], wmx[4];
    if (lane == 0) { wmn[wave] = mn; wmx[wave] = mx; }
    __syncthreads();
    if (t == 0) {
        pmin[bid] = fminf(fminf(wmn[0], wmn[1]), fminf(wmn[2], wmn[3]));
        pmax[bid] = fmaxf(fmaxf(wmx[0], wmx[1]), fmaxf(wmx[2], wmx[3]));
    }
}

// ---------------------------------------------------------------------------
// Kernel 2: fused per-image min/max finalize + histogram via wave ballots
// (no atomics) -> scaled cdf. grid = 32 blocks (bc = b*16+g), 256 threads.
// ---------------------------------------------------------------------------
__global__ __launch_bounds__(256) void k_hist(
        const float* __restrict__ pmin, const float* __restrict__ pmax,
        const float* __restrict__ blocksum,
        float* __restrict__ gmin, float* __restrict__ gmax,
        float* __restrict__ pcdf)       // [2][16][64]
{
    const int bc   = blockIdx.x;
    const int t    = threadIdx.x;
    const int lane = t & 63;
    const int wave = t >> 6;

    __shared__ float s_mn, s_inv;
    if (wave == 0) {
        float mn = (lane < 32) ? pmin[bc * 32 + lane] : INFINITY;
        float mx = (lane < 32) ? pmax[bc * 32 + lane] : -INFINITY;
        #pragma unroll
        for (int st = 32; st > 0; st >>= 1) {
            mn = fminf(mn, __shfl_xor(mn, st, 64));
            mx = fmaxf(mx, __shfl_xor(mx, st, 64));
        }
        if (lane == 0) {
            gmin[bc] = mn; gmax[bc] = mx;
            s_mn = mn; s_inv = 1.0f / (mx - mn + EPSF);
        }
    }
    __syncthreads();
    const float mnv = s_mn;
    const float inv = s_inv;

    int idx0, idx1, idx2, idx3;
    {
        const float* bs = blocksum + bc * 1024;
        #define MKIDX(D, IT) { \
            float bmean = bs[t + (IT)*256] * (1.0f / 1024.0f); \
            float xs = (bmean - mnv) * inv; \
            int id = (int)rintf(xs * 63.0f); \
            D = max(0, min(id, 63)); }
        MKIDX(idx0, 0) MKIDX(idx1, 1) MKIDX(idx2, 2) MKIDX(idx3, 3)
        #undef MKIDX
    }

    // lane l accumulates count of bin l within this wave
    int cnt = 0;
    #pragma unroll 1
    for (int b = 0; b < NBINS; ++b) {
        unsigned long long m0 = __ballot(idx0 == b);
        unsigned long long m1 = __ballot(idx1 == b);
        unsigned long long m2 = __ballot(idx2 == b);
        unsigned long long m3 = __ballot(idx3 == b);
        int p = __popcll(m0) + __popcll(m1) + __popcll(m2) + __popcll(m3);
        cnt += (lane == b) ? p : 0;
    }

    __shared__ int whist[4][NBINS];
    whist[wave][lane] = cnt;
    __syncthreads();

    if (t < NBINS) {
        int h = whist[0][t] + whist[1][t] + whist[2][t] + whist[3][t];
        // inclusive scan over 64 bins (lane == bin)
        #pragma unroll
        for (int d = 1; d < 64; d <<= 1) {
            int v = __shfl_up(h, d, 64);
            if (t >= d) h += v;
        }
        const float scale = 0.5f / (1024.0f + EPSF);   // mean over B pre-applied
        pcdf[bc * NBINS + t] = (float)h * scale;
    }
}

// ---------------------------------------------------------------------------
// Kernel 3: conv1 (16->128ch, 5 taps, ReLU) + depthwise conv2 via WAVE
// SHUFFLES (race-free). grid = 32 blocks x 4 channels; 256 thr = 4ch x 64bins.
// ---------------------------------------------------------------------------
__global__ __launch_bounds__(256) void k_conv12(
        const float* __restrict__ pcdf,
        const float* __restrict__ w1, const float* __restrict__ b1,
        const float* __restrict__ w2, const float* __restrict__ b2,
        float* __restrict__ h2)         // [128][64]
{
    __shared__ float dcdf[GROUPS][NBINS];
    __shared__ float w1s[4 * GROUPS * 5];
    __shared__ float w2s[4][5];

    const int t   = threadIdx.x;
    const int ocb = blockIdx.x * 4;
    const int ocl = t >> 6;              // wave-uniform
    const int k   = t & 63;

    // dcdf = sum of the two pre-scaled b-halves
    for (int o = t; o < GROUPS * NBINS; o += 256)
        ((float*)dcdf)[o] = pcdf[o] + pcdf[GROUPS * NBINS + o];

    // conv1 weights, kh=2 row only: [ocl][ic][tap]
    for (int o = t; o < 4 * GROUPS * 5; o += 256) {
        const int oo  = o / 80;
        const int rem = o - oo * 80;
        const int ic  = rem / 5;
        const int tap = rem - ic * 5;
        w1s[o] = w1[((ocb + oo) * GROUPS + ic) * 25 + 10 + tap];
    }
    if (t < 20) w2s[t / 5][t % 5] = w2[(ocb + t / 5) * 25 + 10 + t % 5];
    __syncthreads();

    // conv1: 80 MACs per thread
    float acc = b1[ocb + ocl];
    const float* wrow = w1s + ocl * 80;
    for (int ic = 0; ic < GROUPS; ++ic) {
        #pragma unroll
        for (int tap = 0; tap < 5; ++tap) {
            const int kk = k - 2 + tap;
            if (kk >= 0 && kk < NBINS)
                acc += wrow[ic * 5 + tap] * dcdf[ic][kk];
        }
    }
    const float c1 = fmaxf(acc, 0.f);

    // depthwise conv2: neighbor bins are neighbor lanes -> shuffles,
    // zero-guards implement the pad-0 border. No LDS hazard possible.
    const float m2 = __shfl_up(c1, 2, 64);
    const float m1 = __shfl_up(c1, 1, 64);
    const float p1 = __shfl_down(c1, 1, 64);
    const float p2 = __shfl_down(c1, 2, 64);
    float a = b2[ocb + ocl];
    a += w2s[ocl][0] * ((k >= 2) ? m2 : 0.f);
    a += w2s[ocl][1] * ((k >= 1) ? m1 : 0.f);
    a += w2s[ocl][2] * c1;
    a += w2s[ocl][3] * ((k <= 62) ? p1 : 0.f);
    a += w2s[ocl][4] * ((k <= 61) ? p2 : 0.f);
    h2[(ocb + ocl) * NBINS + k] = fmaxf(a, 0.f);
}

// ---------------------------------------------------------------------------
// Kernel 4: fused lut-finalize + elementwise remap. grid = NIMG*64 blocks,
// 256 threads. Each block needs only ONE lut row (group g == channel c since
// C/G == 1): conv3 for g (4 waves x 32-MAC partials over L2-resident h2),
// softplus, 64-lane shuffle-scan cumsum, normalize + ramp -> LDS; then stream
// 16 float4/thread with nontemporal stores (keeps x L3-resident).
// ---------------------------------------------------------------------------
__global__ __launch_bounds__(256) void k_apply(
        const float* __restrict__ x,
        const float* __restrict__ gmin, const float* __restrict__ gmax,
        const float* __restrict__ h2,
        const float* __restrict__ w3, const float* __restrict__ b3,
        const float* __restrict__ alpha,
        float* __restrict__ out)
{
    const int img  = blockIdx.x >> 6;
    const int part = blockIdx.x & 63;
    const int c    = img & 15;         // channel == group (C/G == 1)
    const int t    = threadIdx.x;
    const int q    = t >> 6;           // wave 0..3
    const int k    = t & 63;

    __shared__ float partial[4][NBINS];
    __shared__ float lut_s[NBINS];

    // conv3 partial: wave q covers h = q*32 .. q*32+31
    {
        float part_acc = 0.f;
        const float* w3p = w3 + c * HIDDEN + q * 32;   // wave-uniform reads
        const float* h2p = h2 + (q * 32) * NBINS + k;  // coalesced per h
        #pragma unroll 8
        for (int h = 0; h < 32; ++h)
            part_acc += w3p[h] * h2p[h * NBINS];
        partial[q][k] = part_acc;
    }
    __syncthreads();
    if (q == 0) {
        float acc = b3[c] + ((partial[0][k] + partial[1][k])
                           + (partial[2][k] + partial[3][k]));
        float d = fmaxf(acc, 0.f) + log1pf(expf(-fabsf(acc)));  // softplus
        // inclusive scan over 64 bins (lane == bin)
        #pragma unroll
        for (int dd = 1; dd < 64; dd <<= 1) {
            float v = __shfl_up(d, dd, 64);
            if (k >= dd) d += v;
        }
        const float tot = __shfl(d, 63, 64);
        lut_s[k] = d / (tot + EPSF) + (float)k * (1.0f / 63.0f);
    }
    __syncthreads();

    const float mnv = gmin[img];
    const float mxv = gmax[img];
    const float r   = mxv - mnv;
    const float inv = 1.0f / (r + EPSF);
    const float aa  = 1.0f / (1.0f + expf(-alpha[0]));

    const size_t base4 = (size_t)img * (IMG_ELEMS / 4) + (size_t)part * 4096;
    const float4* xin = (const float4*)x;
    nfloat4* o4 = (nfloat4*)out;

    #pragma unroll 2
    for (int it = 0; it < 16; ++it) {
        const size_t f = base4 + (size_t)t + (size_t)it * 256;
        float4 v = xin[f];
        nfloat4 w;
        #define REMAP(DST, SRC) { \
            float x01 = (SRC - mnv) * inv; \
            float pos = x01 * 63.0f; \
            int il = max(0, min((int)floorf(pos), 63)); \
            int ih = min(il + 1, 63); \
            float wt = pos - (float)il; \
            float vlo = lut_s[il], vhi = lut_s[ih]; \
            DST = (aa * fmaf(wt, vhi - vlo, vlo) + (1.0f - aa) * x01) * r + mnv; }
        REMAP(w.x, v.x) REMAP(w.y, v.y) REMAP(w.z, v.z) REMAP(w.w, v.w)
        #undef REMAP
        __builtin_nontemporal_store(w, &o4[f]);
    }
}

// ---------------------------------------------------------------------------
extern "C" void kernel_launch(void* const* d_in, const int* in_sizes, int n_in,
                              void* d_out, int out_size, void* d_ws, size_t ws_size,
                              hipStream_t stream)
{
    const float* x     = (const float*)d_in[0];
    const float* w1    = (const float*)d_in[1];
    const float* b1    = (const float*)d_in[2];
    const float* w2    = (const float*)d_in[3];
    const float* b2    = (const float*)d_in[4];
    const float* w3    = (const float*)d_in[5];
    const float* b3    = (const float*)d_in[6];
    const float* alpha = (const float*)d_in[7];
    float* out = (float*)d_out;

    float* ws = (float*)d_ws;
    float* blocksum = ws;            // 32768
    float* pmin     = ws + 32768;    // 1024
    float* pmax     = ws + 33792;    // 1024
    float* gmin     = ws + 34816;    // 32
    float* gmax     = ws + 34848;    // 32
    float* pcdf     = ws + 34880;    // 2048
    float* h2       = ws + 36928;    // 8192

    k_stats <<<NIMG * 32, 256, 0, stream>>>(x, blocksum, pmin, pmax);
    k_hist  <<<NIMG,      256, 0, stream>>>(pmin, pmax, blocksum, gmin, gmax, pcdf);
    k_conv12<<<32,        256, 0, stream>>>(pcdf, w1, b1, w2, b2, h2);
    k_apply <<<NIMG * 64, 256, 0, stream>>>(x, gmin, gmax, h2, w3, b3, alpha, out);
}